// Round 1
// baseline (507.750 us; speedup 1.0000x reference)
//
#include <hip/hip_runtime.h>
#include <hip/hip_bf16.h>
#include <cmath>

// Problem constants (from reference setup_inputs)
#define Bq   4
#define Lq   4096
#define Wq   2048
#define Hq   8
#define BWq  256
#define Mq   (Bq*Lq)        // 16384 positions
#define CCH  64             // chunks per sequence
#define TCH  (Lq/CCH)       // 64 steps per chunk

typedef __bf16 bf16;
typedef __attribute__((ext_vector_type(8))) __bf16 bf16x8;
typedef __attribute__((ext_vector_type(4))) float  f32x4;

// ---- workspace layout (bytes) ----
// wt    : bf16 [2][H][256(n)][256(k)]  (weights, transposed to n-major)  2 MiB
// c_arr : float [W]   (8 * softplus(a_param))                            8 KiB
// a_arr : float [M*W] (recurrence coefficient a_t, fp32)               128 MiB
// Ac,Hc : float [B*CCH*W] each (per-chunk cumprod / local final h)     2+2 MiB
// carry : float [B*CCH*W]  (chunk carry-in states)                       2 MiB
#define WS_WT    0
#define WS_C     (2*Hq*BWq*BWq*2)            // 2 MiB
#define WS_A     (4u*1024u*1024u)            // 4 MiB (aligned)
#define WS_AC    (WS_A + (size_t)Mq*Wq*4)
#define WS_HC    (WS_AC + (size_t)Bq*CCH*Wq*4)
#define WS_CARRY (WS_HC + (size_t)Bq*CCH*Wq*4)
// total ~144.5 MiB

// ---------------- K0: weight transpose/cast + c vector ----------------
__global__ void prep_weights(const float* __restrict__ ig_w,
                             const float* __restrict__ ag_w,
                             const float* __restrict__ a_param,
                             bf16* __restrict__ wt, float* __restrict__ c_arr) {
    int gid = blockIdx.x * 256 + threadIdx.x;      // 2*8*256*256 = 1048576 total
    int k = gid & 255;
    int n = (gid >> 8) & 255;
    int h = (gid >> 16) & 7;
    int g = gid >> 19;
    const float* src = g ? ag_w : ig_w;
    // wt[g][h][n][k] = w[h][k][n]  (write coalesced; read via L2/L3, tiny)
    wt[gid] = (bf16)src[h*65536 + k*256 + n];
    if (gid < Wq) {
        float ap = a_param[gid];
        c_arr[gid] = 8.0f * log1pf(__expf(ap));    // 8*softplus(a_param)
    }
}

// ---------------- K1: dual-gate bf16 MFMA GEMM + elementwise ----------------
// grid: (M/64, H*4). Block = 256 threads (4 waves, 2x2 wave grid).
// Computes gate_x, gate_a pre-activations for a 64(m) x 64(n) tile of one head,
// then a_t (-> a_arr) and normalized_x (-> y buffer, overwritten later by scan).
#define BM 64
#define BN 64
#define BK 64
#define LDP 72   // LDS row pitch in bf16 elems (64 + 8 pad -> 2-way max conflict)

__global__ __launch_bounds__(256) void gates_kernel(
    const float* __restrict__ x, const int* __restrict__ segpos,
    const bf16* __restrict__ wt, const float* __restrict__ igb,
    const float* __restrict__ agb, const float* __restrict__ c_arr,
    float* __restrict__ a_arr, float* __restrict__ xn_out)
{
    __shared__ __align__(16) bf16 As[BM*LDP];
    __shared__ __align__(16) bf16 Wx[BN*LDP];
    __shared__ __align__(16) bf16 Wa[BN*LDP];

    const int tid  = threadIdx.x;
    const int m0   = blockIdx.x * BM;
    const int h    = blockIdx.y >> 2;
    const int nt   = blockIdx.y & 3;
    const int n0   = nt * BN;

    const int lane = tid & 63;
    const int wid  = tid >> 6;
    const int wm = wid >> 1, wn = wid & 1;
    const int l16 = lane & 15, quad = lane >> 4;

    f32x4 accx[2][2], acca[2][2];
    for (int i = 0; i < 2; i++)
        for (int j = 0; j < 2; j++) {
            accx[i][j] = (f32x4){0.f,0.f,0.f,0.f};
            acca[i][j] = (f32x4){0.f,0.f,0.f,0.f};
        }

    const bf16* wtx = wt + ((size_t)((0*Hq + h)*256 + n0))*256;
    const bf16* wta = wt + ((size_t)((1*Hq + h)*256 + n0))*256;

    for (int kk = 0; kk < BWq; kk += BK) {
        __syncthreads();
        // stage A tile: x[m0..m0+63][h*256+kk .. +63], fp32 -> bf16
        for (int p = 0; p < 2; p++) {
            int lin = p*2048 + tid*8;
            int r = lin >> 6, c = lin & 63;
            const float* gp = x + (size_t)(m0 + r)*Wq + h*256 + kk + c;
            float4 f0 = *(const float4*)gp;
            float4 f1 = *(const float4*)(gp + 4);
            bf16x8 v;
            v[0]=(bf16)f0.x; v[1]=(bf16)f0.y; v[2]=(bf16)f0.z; v[3]=(bf16)f0.w;
            v[4]=(bf16)f1.x; v[5]=(bf16)f1.y; v[6]=(bf16)f1.z; v[7]=(bf16)f1.w;
            *(bf16x8*)&As[r*LDP + c] = v;
        }
        // stage W tiles (already [n][k] bf16 in ws)
        for (int p = 0; p < 2; p++) {
            int lin = p*2048 + tid*8;
            int r = lin >> 6, c = lin & 63;
            *(bf16x8*)&Wx[r*LDP + c] = *(const bf16x8*)&wtx[(size_t)r*256 + kk + c];
            *(bf16x8*)&Wa[r*LDP + c] = *(const bf16x8*)&wta[(size_t)r*256 + kk + c];
        }
        __syncthreads();
        for (int ks = 0; ks < 2; ks++) {
            bf16x8 af[2], bxf[2], baf[2];
            for (int i = 0; i < 2; i++) {
                af[i]  = *(bf16x8*)&As[(wm*32 + i*16 + l16)*LDP + ks*32 + quad*8];
                bxf[i] = *(bf16x8*)&Wx[(wn*32 + i*16 + l16)*LDP + ks*32 + quad*8];
                baf[i] = *(bf16x8*)&Wa[(wn*32 + i*16 + l16)*LDP + ks*32 + quad*8];
            }
            for (int i = 0; i < 2; i++)
                for (int j = 0; j < 2; j++) {
                    accx[i][j] = __builtin_amdgcn_mfma_f32_16x16x32_bf16(af[i], bxf[j], accx[i][j], 0, 0, 0);
                    acca[i][j] = __builtin_amdgcn_mfma_f32_16x16x32_bf16(af[i], baf[j], acca[i][j], 0, 0, 0);
                }
        }
    }

    // epilogue: C/D layout col=lane&15, row=quad*4+reg  [verified gfx950 mapping]
    for (int i = 0; i < 2; i++)
        for (int j = 0; j < 2; j++) {
            int col   = wn*32 + j*16 + l16;
            int wfull = h*256 + n0 + col;
            float bx = igb[wfull], ba = agb[wfull], cc = c_arr[wfull];
            for (int r = 0; r < 4; r++) {
                int row = wm*32 + i*16 + quad*4 + r;
                int m   = m0 + row;
                int l   = m & (Lq - 1);
                bool reset = (segpos[l] == 0);
                float zx = accx[i][j][r] + bx;
                float za = acca[i][j][r] + ba;
                float gx = 1.f / (1.f + __expf(-zx));
                float ga = 1.f / (1.f + __expf(-za));
                float log_a = -ga * cc;
                float a = __expf(log_a);
                // sqrt(1 - a^2) via expm1 (avoids cancellation for a ~ 1)
                float mult = reset ? 1.f : sqrtf(-expm1f(2.f * log_a));
                size_t idx = (size_t)m*Wq + wfull;
                float xv = x[idx];
                a_arr[idx]  = reset ? 0.f : a;
                xn_out[idx] = xv * gx * mult;
            }
        }
}

// ---------------- K2: per-chunk reduce (cumprod A_c, local-scan H_c) ----------------
__global__ __launch_bounds__(256) void chunk_reduce(
    const float* __restrict__ a_arr, const float* __restrict__ xn,
    float* __restrict__ Ac, float* __restrict__ Hc)
{
    int gid = blockIdx.x*256 + threadIdx.x;   // B*CCH*W = 524288, layout (b,c,w)
    int w  = gid & (Wq - 1);
    int bc = gid >> 11;
    int c  = bc & (CCH - 1);
    int b  = bc >> 6;
    size_t base = ((size_t)(b*Lq + c*TCH))*Wq + w;
    float A = 1.f, hloc = 0.f;
    for (int i = 0; i < TCH; i++) {
        float a  = a_arr[base + (size_t)i*Wq];
        float xv = xn  [base + (size_t)i*Wq];
        A *= a;
        hloc = a*hloc + xv;
    }
    Ac[gid] = A;
    Hc[gid] = hloc;
}

// ---------------- K2b: scan over chunks (tiny) ----------------
__global__ __launch_bounds__(256) void chunk_scan(
    const float* __restrict__ Ac, const float* __restrict__ Hc,
    const float* __restrict__ prev_h, float* __restrict__ carry,
    float* __restrict__ last_h)
{
    int gid = blockIdx.x*256 + threadIdx.x;   // B*W = 8192
    int w = gid & (Wq - 1);
    int b = gid >> 11;
    float hcar = prev_h[gid];                 // note: a_t=0 at t=0 (reset) makes this moot, but keep general
    for (int c = 0; c < CCH; c++) {
        int idx = (b*CCH + c)*Wq + w;
        carry[idx] = hcar;
        hcar = Ac[idx]*hcar + Hc[idx];
    }
    last_h[gid] = hcar;
}

// ---------------- K3: apply carries, write y in-place over xn ----------------
__global__ __launch_bounds__(256) void chunk_apply(
    const float* __restrict__ a_arr, const float* __restrict__ carry,
    float* __restrict__ y)
{
    int gid = blockIdx.x*256 + threadIdx.x;
    int w  = gid & (Wq - 1);
    int bc = gid >> 11;
    int c  = bc & (CCH - 1);
    int b  = bc >> 6;
    float h = carry[gid];
    size_t base = ((size_t)(b*Lq + c*TCH))*Wq + w;
    for (int i = 0; i < TCH; i++) {
        size_t idx = base + (size_t)i*Wq;
        h = a_arr[idx]*h + y[idx];   // y currently holds normalized_x
        y[idx] = h;
    }
}

extern "C" void kernel_launch(void* const* d_in, const int* in_sizes, int n_in,
                              void* d_out, int out_size, void* d_ws, size_t ws_size,
                              hipStream_t stream) {
    const float* x       = (const float*)d_in[0];
    const int*   segpos  = (const int*)  d_in[1];
    const float* prev_h  = (const float*)d_in[2];
    const float* ig_w    = (const float*)d_in[3];
    const float* ig_b    = (const float*)d_in[4];
    const float* ag_w    = (const float*)d_in[5];
    const float* ag_b    = (const float*)d_in[6];
    const float* a_param = (const float*)d_in[7];
    float* out = (float*)d_out;                    // [M*W] y, then [B*W] last_h

    char* ws = (char*)d_ws;                        // needs ~144.5 MiB
    bf16*  wt    = (bf16*) (ws + WS_WT);
    float* c_arr = (float*)(ws + WS_C);
    float* a_arr = (float*)(ws + WS_A);
    float* Ac    = (float*)(ws + WS_AC);
    float* Hc    = (float*)(ws + WS_HC);
    float* carry = (float*)(ws + WS_CARRY);

    prep_weights<<<(2*Hq*BWq*BWq)/256, 256, 0, stream>>>(ig_w, ag_w, a_param, wt, c_arr);

    dim3 g1(Mq/BM, Hq*4);
    gates_kernel<<<g1, 256, 0, stream>>>(x, segpos, wt, ig_b, ag_b, c_arr, a_arr, out);

    chunk_reduce<<<(Bq*CCH*Wq)/256, 256, 0, stream>>>(a_arr, out, Ac, Hc);
    chunk_scan  <<<(Bq*Wq)/256,     256, 0, stream>>>(Ac, Hc, prev_h, carry, out + (size_t)Mq*Wq);
    chunk_apply <<<(Bq*CCH*Wq)/256, 256, 0, stream>>>(a_arr, carry, out);
}